// Round 9
// baseline (257.384 us; speedup 1.0000x reference)
//
#include <hip/hip_runtime.h>

#define F_IN 128
#define NBMAX 512      // max coarse buckets (256 nodes each)
#define TILE1 8192     // edges per partition tile
#define CAP   9472     // padded per-bucket capacity (mean 8184, sigma~90 -> 14 sigma)
#define CAP2  10240    // pass-2 LDS staging capacity

typedef __attribute__((ext_vector_type(8))) short short8;
typedef __attribute__((ext_vector_type(4))) float f32x4;
typedef __attribute__((ext_vector_type(2))) float f32x2;

__device__ __forceinline__ unsigned short f2bf(float f) {   // RNE float->bf16
    unsigned u = __float_as_uint(f);
    u += 0x7fffu + ((u >> 16) & 1u);
    return (unsigned short)(u >> 16);
}
__device__ __forceinline__ float bflo(unsigned u) { return __uint_as_float(u << 16); }
__device__ __forceinline__ float bfhi(unsigned u) { return __uint_as_float(u & 0xffff0000u); }

// single f32 -> fp8(e4m3) byte via HW conversion (RNE, saturating)
__device__ __forceinline__ unsigned char f2fp8(float f) {
    return (unsigned char)(__builtin_amdgcn_cvt_pk_fp8_f32(f, f, 0, false) & 0xff);
}

// 32B-row gather (half-G): dword at row c, slot sl (0..7); 32-bit byte offset
__device__ __forceinline__ unsigned ldGH(const unsigned* __restrict__ G,
                                         unsigned c, unsigned sl) {
    return *(const unsigned*)((const char*)G + ((c << 5) + (sl << 2)));
}

// ---- pass 1: LDS-staged partition into padded coarse buckets ----
// bucket b owns ebuf[b*CAP, b*CAP+CAP); blocks claim sub-ranges via cursor atomics
__global__ __launch_bounds__(1024) void k_part1(const int* __restrict__ src,
                                                const int* __restrict__ dst,
                                                int* __restrict__ cursor,
                                                unsigned* __restrict__ ebuf,
                                                int E, int nb) {
    __shared__ unsigned staged[TILE1];
    __shared__ unsigned short sbuck[TILE1];
    __shared__ int hist[NBMAX], lbase[NBMAX], lcur[NBMAX], gbase[NBMAX];
    int t = threadIdx.x;
    for (int i = t; i < nb; i += 1024) hist[i] = 0;
    __syncthreads();
    int base = blockIdx.x * TILE1;
    int end = min(base + TILE1, E);
    int dreg[8];                                  // dst cached in regs: single read
#pragma unroll
    for (int k = 0; k < 8; ++k) {
        int i = base + t + 1024 * k;
        dreg[k] = (i < end) ? dst[i] : -1;
    }
#pragma unroll
    for (int k = 0; k < 8; ++k)
        if (dreg[k] >= 0) atomicAdd(&hist[dreg[k] >> 8], 1);
    __syncthreads();
    if (t < 64) {                                // single-wave chunked scan
        int carry = 0;
        for (int c = 0; c < (nb + 63) / 64; ++c) {
            int idx = c * 64 + t;
            int v = (idx < nb) ? hist[idx] : 0;
            int inc = v;
            for (int d = 1; d < 64; d <<= 1) {
                int u = __shfl_up(inc, d, 64);
                if (t >= d) inc += u;
            }
            if (idx < nb) { int ex = carry + inc - v; lbase[idx] = ex; lcur[idx] = ex; }
            carry += __shfl(inc, 63, 64);
        }
    }
    __syncthreads();
    for (int i = t; i < nb; i += 1024)
        gbase[i] = i * CAP + (hist[i] ? atomicAdd(&cursor[i], hist[i]) : 0);
#pragma unroll
    for (int k = 0; k < 8; ++k) {
        if (dreg[k] < 0) continue;
        int i = base + t + 1024 * k;
        int d = dreg[k];
        int b = d >> 8;
        int r = atomicAdd(&lcur[b], 1);
        staged[r] = ((unsigned)src[i] << 8) | (unsigned)(d & 255);
        sbuck[r] = (unsigned short)b;
    }
    __syncthreads();
    int cnt = end - base;
    for (int i = t; i < cnt; i += 1024) {
        int b = sbuck[i];
        __builtin_nontemporal_store(staged[i], &ebuf[gbase[b] + (i - lbase[b])]);
    }
}

// ---- pass 2: per-bucket 256-bin counting sort; emits csr, offs2{beg,end}, dinv ----
__global__ __launch_bounds__(1024) void k_part2(const unsigned* __restrict__ ebuf,
                                                const int* __restrict__ cursor,
                                                int* __restrict__ csr,
                                                uint2* __restrict__ offs2,
                                                float* __restrict__ dinv, int n) {
    __shared__ unsigned staged[CAP2];
    __shared__ int hist[256], lcur[256];
    int t = threadIdx.x;
    int b = blockIdx.x;
    int beg = b * CAP;
    int cnt = cursor[b];
    int end = beg + cnt;
    if (t < 256) hist[t] = 0;
    __syncthreads();
    for (int i = beg + t; i < end; i += 1024)
        atomicAdd(&hist[ebuf[i] & 255u], 1);
    __syncthreads();
    if (t < 64) {
        int carry = 0;
        for (int c = 0; c < 4; ++c) {
            int idx = c * 64 + t;
            int v = hist[idx];
            int inc = v;
            for (int d = 1; d < 64; d <<= 1) {
                int u = __shfl_up(inc, d, 64);
                if (t >= d) inc += u;
            }
            int ex = carry + inc - v;
            lcur[idx] = ex;
            int node = b * 256 + idx;
            if (node < n) {
                offs2[node] = make_uint2((unsigned)(beg + ex), (unsigned)(beg + ex + v));
                dinv[node] = rsqrtf((float)(v + 1));
            }
            carry += __shfl(inc, 63, 64);
        }
    }
    __syncthreads();
    for (int i = beg + t; i < end; i += 1024) {
        unsigned e = __builtin_nontemporal_load(ebuf + i);
        int r = atomicAdd(&lcur[(int)(e & 255u)], 1);
        staged[r] = e >> 8;
    }
    __syncthreads();
    for (int i = t; i < cnt; i += 1024)
        csr[beg + i] = (int)staged[i];            // plain store: L2-warm for gathers
    if (t < 64) csr[end + t] = n;   // 64-entry load-safety pad (unconditional burst loads)
}

// ---- MFMA GEMM: GA/GB[n][32](fp8 e4m3) = halves of (X[n][K] @ W[K][64]) * dinv[n] ----
// block 0 additionally folds Wfold = W2@Wl1@Wl2, bconst = b2@Wc + bl1@Wl2 + bl2,
// zeroes pad rows GA[n], GB[n] and P[n]
template<int K, bool INBF16>
__global__ __launch_bounds__(256) void k_gemm_mfma(const void* __restrict__ Xv,
                                                   const float* __restrict__ W,
                                                   const float* __restrict__ dinv,
                                                   unsigned* __restrict__ GA,
                                                   unsigned* __restrict__ GB, int n,
                                                   const float* __restrict__ W2,
                                                   const float* __restrict__ b2,
                                                   const float* __restrict__ Wl1,
                                                   const float* __restrict__ bl1,
                                                   const float* __restrict__ Wl2,
                                                   const float* __restrict__ bl2,
                                                   float* __restrict__ Wfold,
                                                   float* __restrict__ bconst,
                                                   float2* __restrict__ P) {
    constexpr int AST = K + 8;
    __shared__ unsigned short A_lds[64 * AST];
    __shared__ unsigned short Wt_lds[64 * AST];
    __shared__ unsigned char C8[64 * 68];   // fp8 staging, row stride 68 B
    __shared__ float Wc[64][2];
    __shared__ float bc0[2];
    int t = threadIdx.x;
    int base = blockIdx.x * 64;

    if (blockIdx.x == 0) {                  // folded k_wfold + pad-row zeroes
        if (t < 128) {
            int k = t >> 1, c = t & 1;
            float s = 0.f;
            for (int m = 0; m < 32; ++m) s += Wl1[k * 32 + m] * Wl2[m * 2 + c];
            Wc[k][c] = s;
        } else if (t < 130) {
            int c = t - 128;
            float s = bl2[c];
            for (int m = 0; m < 32; ++m) s += bl1[m] * Wl2[m * 2 + c];
            bc0[c] = s;
        } else if (t == 200) {
            P[n] = make_float2(0.f, 0.f);         // zero pad row P[n]
        } else if (t >= 240 && t < 248) {
            GA[(size_t)n * 8 + (t - 240)] = 0u;   // zero row GA[n]
        } else if (t >= 248) {
            GB[(size_t)n * 8 + (t - 248)] = 0u;   // zero row GB[n]
        }
        __syncthreads();
        if (t < 128) {
            int k = t >> 1, c = t & 1;
            float s = 0.f;
            for (int j = 0; j < 64; ++j) s += W2[k * 64 + j] * Wc[j][c];
            Wfold[k * 2 + c] = s;
        } else if (t < 130) {
            int c = t - 128;
            float s = bc0[c];
            for (int j = 0; j < 64; ++j) s += b2[j] * Wc[j][c];
            bconst[c] = s;
        }
    }

    for (int idx = t; idx < K * 64; idx += 256) {
        int k = idx >> 6, nn = idx & 63;
        Wt_lds[nn * AST + k] = f2bf(W[idx]);
    }
    if (!INBF16) {
        const f32x4* X4 = (const f32x4*)Xv;
        constexpr int F4 = K / 4;
        for (int idx = t; idx < 64 * F4; idx += 256) {
            int row = idx / F4, c4 = idx % F4;
            f32x4 f = {0.f, 0.f, 0.f, 0.f};
            if (base + row < n) f = X4[(size_t)base * F4 + idx];
            unsigned p0 = (unsigned)f2bf(f.x) | ((unsigned)f2bf(f.y) << 16);
            unsigned p1 = (unsigned)f2bf(f.z) | ((unsigned)f2bf(f.w) << 16);
            *(uint2*)&A_lds[row * AST + c4 * 4] = make_uint2(p0, p1);
        }
    } else {
        const unsigned* H32 = (const unsigned*)Xv;
        constexpr int U2 = K / 2;
        for (int idx = t; idx < 64 * U2; idx += 256) {
            int row = idx / U2, c2 = idx % U2;
            unsigned u = 0;
            if (base + row < n) u = H32[(size_t)base * U2 + idx];
            *(unsigned*)&A_lds[row * AST + c2 * 2] = u;
        }
    }
    __syncthreads();

    int lane = t & 63, w = t >> 6;
    int q = lane >> 4, m = lane & 15;
    f32x4 acc0 = {0,0,0,0}, acc1 = {0,0,0,0}, acc2 = {0,0,0,0}, acc3 = {0,0,0,0};
    const unsigned short* arow = &A_lds[(16 * w + m) * AST + q * 8];
#pragma unroll
    for (int s = 0; s < K / 32; ++s) {
        short8 a  = *(const short8*)(arow + s * 32);
        short8 w0 = *(const short8*)&Wt_lds[ m       * AST + s * 32 + q * 8];
        short8 w1 = *(const short8*)&Wt_lds[(16 + m) * AST + s * 32 + q * 8];
        short8 w2 = *(const short8*)&Wt_lds[(32 + m) * AST + s * 32 + q * 8];
        short8 w3 = *(const short8*)&Wt_lds[(48 + m) * AST + s * 32 + q * 8];
        acc0 = __builtin_amdgcn_mfma_f32_16x16x32_bf16(a, w0, acc0, 0, 0, 0);
        acc1 = __builtin_amdgcn_mfma_f32_16x16x32_bf16(a, w1, acc1, 0, 0, 0);
        acc2 = __builtin_amdgcn_mfma_f32_16x16x32_bf16(a, w2, acc2, 0, 0, 0);
        acc3 = __builtin_amdgcn_mfma_f32_16x16x32_bf16(a, w3, acc3, 0, 0, 0);
    }
    float dv[4];
#pragma unroll
    for (int r = 0; r < 4; ++r) {
        int node = base + 16 * w + q * 4 + r;
        dv[r] = (node < n) ? dinv[node] : 0.f;
    }
#pragma unroll
    for (int r = 0; r < 4; ++r) {
        int row = 16 * w + q * 4 + r;
        C8[row * 68 + m]      = f2fp8(acc0[r] * dv[r]);
        C8[row * 68 + 16 + m] = f2fp8(acc1[r] * dv[r]);
        C8[row * 68 + 32 + m] = f2fp8(acc2[r] * dv[r]);
        C8[row * 68 + 48 + m] = f2fp8(acc3[r] * dv[r]);
    }
    __syncthreads();
    for (int idx = t; idx < 1024; idx += 256) {
        int row = idx >> 4, c4 = idx & 15;
        int node = base + row;
        if (node < n) {
            unsigned v = *(const unsigned*)&C8[row * 68 + c4 * 4];
            if (c4 < 8) GA[(size_t)node * 8 + c4] = v;        // dims 0..31
            else        GB[(size_t)node * 8 + (c4 - 8)] = v;  // dims 32..63
        }
    }
}

// ---- gather pass A: sum GA (dims 0..31, L2-resident 3.2MB) -> HA[n][32] bf16 ----
// 8 lanes/row; 64-edge bursts: 8 csr + 8 G loads in flight; OOB -> zero row GA[n]
__global__ __launch_bounds__(256) void k_gfoldA(const int* __restrict__ csr,
                                                const uint2* __restrict__ offs2,
                                                const unsigned* __restrict__ GA,
                                                uint2* __restrict__ HA, int n) {
    int w = (blockIdx.x * 256 + threadIdx.x) >> 6;
    if (w >= n) return;
    int lane = threadIdx.x & 63;
    unsigned g = (unsigned)lane >> 3, sl = (unsigned)lane & 7u;
    uint2 o = offs2[w];
    int beg = (int)o.x, end = (int)o.y;
    f32x2 A01 = {0.f, 0.f}, A23 = {0.f, 0.f};
    unsigned selfU = ldGH(GA, (unsigned)w, sl);
    for (int e = beg; e < end; e += 64) {
        int i0 = e + (int)g;
        int vv[8];
#pragma unroll
        for (int k = 0; k < 8; ++k)               // unconditional: bucket pad makes safe
            vv[k] = csr[i0 + 8 * k];
        unsigned uu[8];
#pragma unroll
        for (int k = 0; k < 8; ++k) {
            unsigned c = (i0 + 8 * k < end) ? (unsigned)vv[k] : (unsigned)n;
            uu[k] = ldGH(GA, c, sl);
        }
#pragma unroll
        for (int k = 0; k < 8; ++k) {
            A01 += __builtin_amdgcn_cvt_pk_f32_fp8((int)uu[k], false);
            A23 += __builtin_amdgcn_cvt_pk_f32_fp8((int)uu[k], true);
        }
    }
    float a0 = A01.x, a1 = A01.y, a2 = A23.x, a3 = A23.y;
#pragma unroll
    for (int m = 8; m <= 32; m <<= 1) {           // merge 8 edge-groups
        a0 += __shfl_xor(a0, m, 64); a1 += __shfl_xor(a1, m, 64);
        a2 += __shfl_xor(a2, m, 64); a3 += __shfl_xor(a3, m, 64);
    }
    f32x2 s0 = __builtin_amdgcn_cvt_pk_f32_fp8((int)selfU, false);
    f32x2 s1 = __builtin_amdgcn_cvt_pk_f32_fp8((int)selfU, true);
    a0 += s0.x; a1 += s0.y; a2 += s1.x; a3 += s1.y;
    if (g == 0) {                                 // lanes 0..7 write 4 dims as bf16
        unsigned p0 = (unsigned)f2bf(a0) | ((unsigned)f2bf(a1) << 16);
        unsigned p1 = (unsigned)f2bf(a2) | ((unsigned)f2bf(a3) << 16);
        HA[(size_t)w * 8 + sl] = make_uint2(p0, p1);
    }
}

// ---- gather pass B: sum GB (dims 32..63) + HA -> relu/fold -> P ----
__global__ __launch_bounds__(256) void k_gfoldB(const int* __restrict__ csr,
                                                const uint2* __restrict__ offs2,
                                                const unsigned* __restrict__ GB,
                                                const uint2* __restrict__ HA,
                                                const float* __restrict__ dinv,
                                                const float* __restrict__ bias,
                                                const float* __restrict__ Wfold,
                                                float2* __restrict__ P, int n) {
    int w = (blockIdx.x * 256 + threadIdx.x) >> 6;
    if (w >= n) return;
    int lane = threadIdx.x & 63;
    unsigned g = (unsigned)lane >> 3, sl = (unsigned)lane & 7u;
    uint2 o = offs2[w];
    int beg = (int)o.x, end = (int)o.y;
    f32x2 B01 = {0.f, 0.f}, B23 = {0.f, 0.f};
    unsigned selfU = ldGH(GB, (unsigned)w, sl);
    for (int e = beg; e < end; e += 64) {
        int i0 = e + (int)g;
        int vv[8];
#pragma unroll
        for (int k = 0; k < 8; ++k)
            vv[k] = csr[i0 + 8 * k];
        unsigned uu[8];
#pragma unroll
        for (int k = 0; k < 8; ++k) {
            unsigned c = (i0 + 8 * k < end) ? (unsigned)vv[k] : (unsigned)n;
            uu[k] = ldGH(GB, c, sl);
        }
#pragma unroll
        for (int k = 0; k < 8; ++k) {
            B01 += __builtin_amdgcn_cvt_pk_f32_fp8((int)uu[k], false);
            B23 += __builtin_amdgcn_cvt_pk_f32_fp8((int)uu[k], true);
        }
    }
    float b0 = B01.x, b1v = B01.y, b2v = B23.x, b3 = B23.y;
#pragma unroll
    for (int m = 8; m <= 32; m <<= 1) {
        b0 += __shfl_xor(b0, m, 64); b1v += __shfl_xor(b1v, m, 64);
        b2v += __shfl_xor(b2v, m, 64); b3 += __shfl_xor(b3, m, 64);
    }
    f32x2 s0 = __builtin_amdgcn_cvt_pk_f32_fp8((int)selfU, false);
    f32x2 s1 = __builtin_amdgcn_cvt_pk_f32_fp8((int)selfU, true);
    b0 += s0.x; b1v += s0.y; b2v += s1.x; b3 += s1.y;
    // A-half raw sums from HA (bf16)
    uint2 h = HA[(size_t)w * 8 + sl];
    float a0 = bflo(h.x), a1 = bfhi(h.x), a2 = bflo(h.y), a3 = bfhi(h.y);
    float d = dinv[w];
    float4 bA = ((const float4*)bias)[sl];        // b1 dims 4sl..4sl+3
    float4 bB = ((const float4*)bias)[8 + sl];    // b1 dims 32+4sl..32+4sl+3
    float v0 = fmaxf(fmaf(a0, d, bA.x), 0.f);
    float v1 = fmaxf(fmaf(a1, d, bA.y), 0.f);
    float v2 = fmaxf(fmaf(a2, d, bA.z), 0.f);
    float v3 = fmaxf(fmaf(a3, d, bA.w), 0.f);
    float v4 = fmaxf(fmaf(b0, d, bB.x), 0.f);
    float v5 = fmaxf(fmaf(b1v, d, bB.y), 0.f);
    float v6 = fmaxf(fmaf(b2v, d, bB.z), 0.f);
    float v7 = fmaxf(fmaf(b3, d, bB.w), 0.f);
    float4 wa0 = ((const float4*)Wfold)[2 * sl];        // dims 4sl, 4sl+1
    float4 wa1 = ((const float4*)Wfold)[2 * sl + 1];    // dims 4sl+2, 4sl+3
    float4 wb0 = ((const float4*)Wfold)[16 + 2 * sl];   // dims 32+4sl, 32+4sl+1
    float4 wb1 = ((const float4*)Wfold)[16 + 2 * sl + 1];
    float px = v0 * wa0.x + v1 * wa0.z + v2 * wa1.x + v3 * wa1.z
             + v4 * wb0.x + v5 * wb0.z + v6 * wb1.x + v7 * wb1.z;
    float py = v0 * wa0.y + v1 * wa0.w + v2 * wa1.y + v3 * wa1.w
             + v4 * wb0.y + v5 * wb0.w + v6 * wb1.y + v7 * wb1.w;
    px += __shfl_xor(px, 1, 64); py += __shfl_xor(py, 1, 64);
    px += __shfl_xor(px, 2, 64); py += __shfl_xor(py, 2, 64);
    px += __shfl_xor(px, 4, 64); py += __shfl_xor(py, 4, 64);
    if (lane == 0) P[w] = make_float2(px * d, py * d);
}

// ---- gather-2 on P + fused softmax partials; 16-lane group per node ----
__global__ __launch_bounds__(256) void k_gather2(const int* __restrict__ csr,
                                                 const uint2* __restrict__ offs2,
                                                 const float2* __restrict__ P,
                                                 const float* __restrict__ dinv,
                                                 const float* __restrict__ bconst,
                                                 float* __restrict__ logits,
                                                 float4* __restrict__ partials, int n) {
    __shared__ float sml[16][2];
    int t = threadIdx.x;
    int w = (blockIdx.x * 256 + t) >> 4;
    int sl = t & 15;
    int grp = t >> 4;
    bool valid = (w < n);
    uint2 o = valid ? offs2[w] : make_uint2(0u, 0u);
    int beg = (int)o.x, end = (int)o.y;
    float ax = 0.f, ay = 0.f;
    for (int e = beg; e < end; e += 64) {
        int i0 = e + sl;
        int vv[4];
#pragma unroll
        for (int k = 0; k < 4; ++k)               // unconditional: bucket pad makes safe
            vv[k] = csr[i0 + 16 * k];
#pragma unroll
        for (int k = 0; k < 4; ++k) {
            unsigned j = (i0 + 16 * k < end) ? (unsigned)vv[k] : (unsigned)n;
            float2 p = *(const float2*)((const char*)P + (j << 3));
            ax += p.x; ay += p.y;
        }
    }
    ax += __shfl_xor(ax, 1, 64); ay += __shfl_xor(ay, 1, 64);
    ax += __shfl_xor(ax, 2, 64); ay += __shfl_xor(ay, 2, 64);
    ax += __shfl_xor(ax, 4, 64); ay += __shfl_xor(ay, 4, 64);
    ax += __shfl_xor(ax, 8, 64); ay += __shfl_xor(ay, 8, 64);
    float l0 = -3.4e38f, l1 = -3.4e38f;
    if (valid && sl == 0) {
        float2 self = P[w];
        float d = dinv[w];
        l0 = d * (self.x + ax) + bconst[0];
        l1 = d * (self.y + ay) + bconst[1];
        logits[w * 2]     = l0;
        logits[w * 2 + 1] = l1;
    }
    if (sl == 0) { sml[grp][0] = l0; sml[grp][1] = l1; }
    __syncthreads();
    if (t < 16) {                                 // block softmax partial (16 nodes)
        float a = sml[t][0], bv = sml[t][1];
        float m0 = a, m1 = bv;
#pragma unroll
        for (int d = 1; d < 16; d <<= 1) {
            m0 = fmaxf(m0, __shfl_xor(m0, d, 64));
            m1 = fmaxf(m1, __shfl_xor(m1, d, 64));
        }
        float e0 = (a > -1e38f) ? __expf(a - m0) : 0.f;
        float e1 = (bv > -1e38f) ? __expf(bv - m1) : 0.f;
#pragma unroll
        for (int d = 1; d < 16; d <<= 1) {
            e0 += __shfl_xor(e0, d, 64);
            e1 += __shfl_xor(e1, d, 64);
        }
        if (t == 0) partials[blockIdx.x] = make_float4(m0, e0, m1, e1);
    }
}

// ---- softmax finalize: each block merges all partials, then normalizes ----
__global__ __launch_bounds__(256) void k_sm_final(const float* __restrict__ logits,
                                                  const float4* __restrict__ partials,
                                                  float* __restrict__ out, int n, int nbp) {
    __shared__ float m0s[256], s0s[256], m1s[256], s1s[256];
    int t = threadIdx.x;
    float m0 = -3.4e38f, s0 = 0.f, m1 = -3.4e38f, s1 = 0.f;
    for (int i = t; i < nbp; i += 256) {
        float4 p = partials[i];
        float M = fmaxf(m0, p.x);
        s0 = s0 * __expf(m0 - M) + p.y * __expf(p.x - M); m0 = M;
        M = fmaxf(m1, p.z);
        s1 = s1 * __expf(m1 - M) + p.w * __expf(p.z - M); m1 = M;
    }
    m0s[t] = m0; s0s[t] = s0; m1s[t] = m1; s1s[t] = s1;
    __syncthreads();
    for (int s = 128; s > 0; s >>= 1) {
        if (t < s) {
            float Ma = m0s[t], Mb = m0s[t + s];
            float M = fmaxf(Ma, Mb);
            s0s[t] = s0s[t] * __expf(Ma - M) + s0s[t + s] * __expf(Mb - M);
            m0s[t] = M;
            Ma = m1s[t]; Mb = m1s[t + s];
            M = fmaxf(Ma, Mb);
            s1s[t] = s1s[t] * __expf(Ma - M) + s1s[t + s] * __expf(Mb - M);
            m1s[t] = M;
        }
        __syncthreads();
    }
    float M0 = m0s[0], inv0 = 1.f / s0s[0];
    float M1 = m1s[0], inv1 = 1.f / s1s[0];
    int i = blockIdx.x * 256 + t;
    if (i < n) {
        out[i * 2]     = __expf(logits[i * 2]     - M0) * inv0;
        out[i * 2 + 1] = __expf(logits[i * 2 + 1] - M1) * inv1;
    }
}

extern "C" void kernel_launch(void* const* d_in, const int* in_sizes, int n_in,
                              void* d_out, int out_size, void* d_ws, size_t ws_size,
                              hipStream_t stream) {
    const float* x   = (const float*)d_in[0];
    const int*   ei  = (const int*)d_in[1];
    const float* W1  = (const float*)d_in[2];
    const float* b1  = (const float*)d_in[3];
    const float* W2  = (const float*)d_in[4];
    const float* b2  = (const float*)d_in[5];
    const float* Wl1 = (const float*)d_in[6];
    const float* bl1 = (const float*)d_in[7];
    const float* Wl2 = (const float*)d_in[8];
    const float* bl2 = (const float*)d_in[9];
    float* out = (float*)d_out;

    int N = in_sizes[0] / F_IN;   // 100000
    int E = in_sizes[1] / 2;      // 3200000
    const int* esrc = ei;
    const int* edst = ei + E;

    int nbuck = (N + 255) / 256;  // 391 coarse buckets of 256 nodes

    char* ws = (char*)d_ws;
    size_t off = 0;
    auto alloc = [&](size_t bytes) { void* p = ws + off; off += (bytes + 255) & ~(size_t)255; return p; };
    int*            cursor = (int*)alloc((size_t)NBMAX * 4);
    float*          dinv   = (float*)alloc((size_t)N * 4);
    uint2*          offs2  = (uint2*)alloc((size_t)N * 8);               // {beg,end}/node
    int*            csr    = (int*)alloc((size_t)nbuck * CAP * 4);       // 14.8 MB padded
    unsigned*       ebuf   = (unsigned*)alloc((size_t)nbuck * CAP * 4);  // 14.8 MB padded
    unsigned*       GA     = (unsigned*)alloc((size_t)(N + 1) * 32);     // 3.2 MB fp8 half
    unsigned*       GB     = (unsigned*)alloc((size_t)(N + 1) * 32);     // 3.2 MB fp8 half
    uint2*          HA     = (uint2*)alloc((size_t)N * 64);              // 6.4 MB bf16 sums
    float*          Wfold  = (float*)alloc(64 * 2 * 4);
    float*          bconst = (float*)alloc(2 * 4);
    float2*         P      = (float2*)alloc((size_t)(N + 1) * 8);        // + zero pad row
    float*          logits = (float*)alloc((size_t)N * 2 * 4);
    int qb = (N * 16 + 255) / 256;         // gather2 blocks (16 nodes each)
    float4*         partials = (float4*)alloc((size_t)qb * 16);

    hipMemsetAsync(cursor, 0, NBMAX * sizeof(int), stream);

    int tiles = (E + TILE1 - 1) / TILE1;   // 391
    int mb = (N + 63) / 64;
    int wb = (N * 64 + 255) / 256;         // wave-per-node grid (gfoldA/B)
    int nb = (N + 255) / 256;

    // CSR build (padded-bucket layout)
    k_part1<<<tiles, 1024, 0, stream>>>(esrc, edst, cursor, ebuf, E, nbuck);
    k_part2<<<nbuck, 1024, 0, stream>>>(ebuf, cursor, csr, offs2, dinv, N);

    // layer 1 GEMM: GA/GB = fp8 halves of (x@W1)*dinv ; block 0 folds consts + pads
    k_gemm_mfma<128, false><<<mb, 256, 0, stream>>>(x, W1, dinv, GA, GB, N,
                                                    W2, b2, Wl1, bl1, Wl2, bl2,
                                                    Wfold, bconst, P);

    // gather pass A (GA L2-resident) -> HA ; pass B (GB) + HA -> relu/fold -> P
    k_gfoldA<<<wb, 256, 0, stream>>>(csr, offs2, GA, HA, N);
    k_gfoldB<<<wb, 256, 0, stream>>>(csr, offs2, GB, HA, dinv, b1, Wfold, P, N);

    // gather-2 on P -> logits + per-block softmax partials
    k_gather2<<<qb, 256, 0, stream>>>(csr, offs2, P, dinv, bconst, logits, partials, N);

    // softmax finalize (merge partials + normalize)
    k_sm_final<<<nb, 256, 0, stream>>>(logits, partials, out, N, qb);
}

// Round 10
// 228.027 us; speedup vs baseline: 1.1287x; 1.1287x over previous
//
#include <hip/hip_runtime.h>

#define F_IN 128
#define NBMAX 512      // max coarse buckets (256 nodes each)
#define TILE1 8192     // edges per partition tile
#define CAP   9472     // padded per-bucket capacity (mean 8184, sigma~90 -> 14 sigma)
#define CAP2  10240    // pass-2 LDS staging capacity

typedef __attribute__((ext_vector_type(8))) short short8;
typedef __attribute__((ext_vector_type(4))) float f32x4;
typedef __attribute__((ext_vector_type(2))) float f32x2;

__device__ __forceinline__ unsigned short f2bf(float f) {   // RNE float->bf16
    unsigned u = __float_as_uint(f);
    u += 0x7fffu + ((u >> 16) & 1u);
    return (unsigned short)(u >> 16);
}

// single f32 -> fp8(e4m3) byte via HW conversion (RNE, saturating)
__device__ __forceinline__ unsigned char f2fp8(float f) {
    return (unsigned char)(__builtin_amdgcn_cvt_pk_fp8_f32(f, f, 0, false) & 0xff);
}

// G row gather with 32-bit byte offset -> saddr-form global_load (1 VALU/addr)
__device__ __forceinline__ unsigned ldG(const unsigned* __restrict__ G,
                                        unsigned c, unsigned sl) {
    return *(const unsigned*)((const char*)G + ((c << 6) + (sl << 2)));
}

// ---- pass 1: LDS-staged partition into padded coarse buckets ----
// bucket b owns ebuf[b*CAP, b*CAP+CAP); blocks claim sub-ranges via cursor atomics
__global__ __launch_bounds__(1024) void k_part1(const int* __restrict__ src,
                                                const int* __restrict__ dst,
                                                int* __restrict__ cursor,
                                                unsigned* __restrict__ ebuf,
                                                int E, int nb) {
    __shared__ unsigned staged[TILE1];
    __shared__ unsigned short sbuck[TILE1];
    __shared__ int hist[NBMAX], lbase[NBMAX], lcur[NBMAX], gbase[NBMAX];
    int t = threadIdx.x;
    for (int i = t; i < nb; i += 1024) hist[i] = 0;
    __syncthreads();
    int base = blockIdx.x * TILE1;
    int end = min(base + TILE1, E);
    int dreg[8];                                  // dst cached in regs: single read
#pragma unroll
    for (int k = 0; k < 8; ++k) {
        int i = base + t + 1024 * k;
        dreg[k] = (i < end) ? dst[i] : -1;
    }
#pragma unroll
    for (int k = 0; k < 8; ++k)
        if (dreg[k] >= 0) atomicAdd(&hist[dreg[k] >> 8], 1);
    __syncthreads();
    if (t < 64) {                                // single-wave chunked scan
        int carry = 0;
        for (int c = 0; c < (nb + 63) / 64; ++c) {
            int idx = c * 64 + t;
            int v = (idx < nb) ? hist[idx] : 0;
            int inc = v;
            for (int d = 1; d < 64; d <<= 1) {
                int u = __shfl_up(inc, d, 64);
                if (t >= d) inc += u;
            }
            if (idx < nb) { int ex = carry + inc - v; lbase[idx] = ex; lcur[idx] = ex; }
            carry += __shfl(inc, 63, 64);
        }
    }
    __syncthreads();
    for (int i = t; i < nb; i += 1024)
        gbase[i] = i * CAP + (hist[i] ? atomicAdd(&cursor[i], hist[i]) : 0);
#pragma unroll
    for (int k = 0; k < 8; ++k) {
        if (dreg[k] < 0) continue;
        int i = base + t + 1024 * k;
        int d = dreg[k];
        int b = d >> 8;
        int r = atomicAdd(&lcur[b], 1);
        staged[r] = ((unsigned)src[i] << 8) | (unsigned)(d & 255);
        sbuck[r] = (unsigned short)b;
    }
    __syncthreads();
    int cnt = end - base;
    for (int i = t; i < cnt; i += 1024) {
        int b = sbuck[i];
        __builtin_nontemporal_store(staged[i], &ebuf[gbase[b] + (i - lbase[b])]);
    }
}

// ---- pass 2: per-bucket 256-bin counting sort; emits csr, offs2{beg,end}, dinv ----
__global__ __launch_bounds__(1024) void k_part2(const unsigned* __restrict__ ebuf,
                                                const int* __restrict__ cursor,
                                                int* __restrict__ csr,
                                                uint2* __restrict__ offs2,
                                                float* __restrict__ dinv, int n) {
    __shared__ unsigned staged[CAP2];
    __shared__ int hist[256], lcur[256];
    int t = threadIdx.x;
    int b = blockIdx.x;
    int beg = b * CAP;
    int cnt = cursor[b];
    int end = beg + cnt;
    if (t < 256) hist[t] = 0;
    __syncthreads();
    for (int i = beg + t; i < end; i += 1024)
        atomicAdd(&hist[ebuf[i] & 255u], 1);
    __syncthreads();
    if (t < 64) {
        int carry = 0;
        for (int c = 0; c < 4; ++c) {
            int idx = c * 64 + t;
            int v = hist[idx];
            int inc = v;
            for (int d = 1; d < 64; d <<= 1) {
                int u = __shfl_up(inc, d, 64);
                if (t >= d) inc += u;
            }
            int ex = carry + inc - v;
            lcur[idx] = ex;
            int node = b * 256 + idx;
            if (node < n) {
                offs2[node] = make_uint2((unsigned)(beg + ex), (unsigned)(beg + ex + v));
                dinv[node] = rsqrtf((float)(v + 1));
            }
            carry += __shfl(inc, 63, 64);
        }
    }
    __syncthreads();
    for (int i = beg + t; i < end; i += 1024) {
        unsigned e = __builtin_nontemporal_load(ebuf + i);
        int r = atomicAdd(&lcur[(int)(e & 255u)], 1);
        staged[r] = e >> 8;
    }
    __syncthreads();
    for (int i = t; i < cnt; i += 1024)
        csr[beg + i] = (int)staged[i];            // plain store: L2-warm for gathers
    if (t < 64) csr[end + t] = n;   // 64-entry load-safety pad (unconditional burst loads)
}

// ---- MFMA GEMM: G[n][64](fp8 e4m3) = (X[n][K] @ W[K][64]) * dinv[n] ----
// block 0 additionally folds Wfold = W2@Wl1@Wl2, bconst = b2@Wc + bl1@Wl2 + bl2,
// zeroes pad rows G[n] and P[n]
template<int K, bool INBF16>
__global__ __launch_bounds__(256) void k_gemm_mfma(const void* __restrict__ Xv,
                                                   const float* __restrict__ W,
                                                   const float* __restrict__ dinv,
                                                   unsigned* __restrict__ G, int n,
                                                   const float* __restrict__ W2,
                                                   const float* __restrict__ b2,
                                                   const float* __restrict__ Wl1,
                                                   const float* __restrict__ bl1,
                                                   const float* __restrict__ Wl2,
                                                   const float* __restrict__ bl2,
                                                   float* __restrict__ Wfold,
                                                   float* __restrict__ bconst,
                                                   float2* __restrict__ P) {
    constexpr int AST = K + 8;
    __shared__ unsigned short A_lds[64 * AST];
    __shared__ unsigned short Wt_lds[64 * AST];
    __shared__ unsigned char C8[64 * 68];   // fp8 staging, row stride 68 B
    __shared__ float Wc[64][2];
    __shared__ float bc0[2];
    int t = threadIdx.x;
    int base = blockIdx.x * 64;

    if (blockIdx.x == 0) {                  // folded k_wfold + pad-row zeroes
        if (t < 128) {
            int k = t >> 1, c = t & 1;
            float s = 0.f;
            for (int m = 0; m < 32; ++m) s += Wl1[k * 32 + m] * Wl2[m * 2 + c];
            Wc[k][c] = s;
        } else if (t < 130) {
            int c = t - 128;
            float s = bl2[c];
            for (int m = 0; m < 32; ++m) s += bl1[m] * Wl2[m * 2 + c];
            bc0[c] = s;
        } else if (t == 200) {
            P[n] = make_float2(0.f, 0.f);         // zero pad row P[n]
        } else if (t >= 240 && t < 256) {
            G[(size_t)n * 16 + (t - 240)] = 0u;   // zero row G[n]
        }
        __syncthreads();
        if (t < 128) {
            int k = t >> 1, c = t & 1;
            float s = 0.f;
            for (int j = 0; j < 64; ++j) s += W2[k * 64 + j] * Wc[j][c];
            Wfold[k * 2 + c] = s;
        } else if (t < 130) {
            int c = t - 128;
            float s = bc0[c];
            for (int j = 0; j < 64; ++j) s += b2[j] * Wc[j][c];
            bconst[c] = s;
        }
    }

    for (int idx = t; idx < K * 64; idx += 256) {
        int k = idx >> 6, nn = idx & 63;
        Wt_lds[nn * AST + k] = f2bf(W[idx]);
    }
    if (!INBF16) {
        const f32x4* X4 = (const f32x4*)Xv;
        constexpr int F4 = K / 4;
        for (int idx = t; idx < 64 * F4; idx += 256) {
            int row = idx / F4, c4 = idx % F4;
            f32x4 f = {0.f, 0.f, 0.f, 0.f};
            if (base + row < n) f = X4[(size_t)base * F4 + idx];
            unsigned p0 = (unsigned)f2bf(f.x) | ((unsigned)f2bf(f.y) << 16);
            unsigned p1 = (unsigned)f2bf(f.z) | ((unsigned)f2bf(f.w) << 16);
            *(uint2*)&A_lds[row * AST + c4 * 4] = make_uint2(p0, p1);
        }
    } else {
        const unsigned* H32 = (const unsigned*)Xv;
        constexpr int U2 = K / 2;
        for (int idx = t; idx < 64 * U2; idx += 256) {
            int row = idx / U2, c2 = idx % U2;
            unsigned u = 0;
            if (base + row < n) u = H32[(size_t)base * U2 + idx];
            *(unsigned*)&A_lds[row * AST + c2 * 2] = u;
        }
    }
    __syncthreads();

    int lane = t & 63, w = t >> 6;
    int q = lane >> 4, m = lane & 15;
    f32x4 acc0 = {0,0,0,0}, acc1 = {0,0,0,0}, acc2 = {0,0,0,0}, acc3 = {0,0,0,0};
    const unsigned short* arow = &A_lds[(16 * w + m) * AST + q * 8];
#pragma unroll
    for (int s = 0; s < K / 32; ++s) {
        short8 a  = *(const short8*)(arow + s * 32);
        short8 w0 = *(const short8*)&Wt_lds[ m       * AST + s * 32 + q * 8];
        short8 w1 = *(const short8*)&Wt_lds[(16 + m) * AST + s * 32 + q * 8];
        short8 w2 = *(const short8*)&Wt_lds[(32 + m) * AST + s * 32 + q * 8];
        short8 w3 = *(const short8*)&Wt_lds[(48 + m) * AST + s * 32 + q * 8];
        acc0 = __builtin_amdgcn_mfma_f32_16x16x32_bf16(a, w0, acc0, 0, 0, 0);
        acc1 = __builtin_amdgcn_mfma_f32_16x16x32_bf16(a, w1, acc1, 0, 0, 0);
        acc2 = __builtin_amdgcn_mfma_f32_16x16x32_bf16(a, w2, acc2, 0, 0, 0);
        acc3 = __builtin_amdgcn_mfma_f32_16x16x32_bf16(a, w3, acc3, 0, 0, 0);
    }
    float dv[4];
#pragma unroll
    for (int r = 0; r < 4; ++r) {
        int node = base + 16 * w + q * 4 + r;
        dv[r] = (node < n) ? dinv[node] : 0.f;
    }
#pragma unroll
    for (int r = 0; r < 4; ++r) {
        int row = 16 * w + q * 4 + r;
        C8[row * 68 + m]      = f2fp8(acc0[r] * dv[r]);
        C8[row * 68 + 16 + m] = f2fp8(acc1[r] * dv[r]);
        C8[row * 68 + 32 + m] = f2fp8(acc2[r] * dv[r]);
        C8[row * 68 + 48 + m] = f2fp8(acc3[r] * dv[r]);
    }
    __syncthreads();
    for (int idx = t; idx < 1024; idx += 256) {
        int row = idx >> 4, c4 = idx & 15;
        int node = base + row;
        if (node < n) G[(size_t)node * 16 + c4] = *(const unsigned*)&C8[row * 68 + c4 * 4];
    }
}

// ---- gather-1 + fused fold on fp8 G; 16 lanes/row ----
// 64-edge bursts: 16 csr loads (unconditional, pad-safe) + 16 G loads in flight;
// OOB slots value-clamp to zero row G[n]
__global__ __launch_bounds__(256) void k_gfold(const int* __restrict__ csr,
                                               const uint2* __restrict__ offs2,
                                               const unsigned* __restrict__ G,
                                               const float* __restrict__ dinv,
                                               const float* __restrict__ bias,
                                               const float* __restrict__ Wfold,
                                               float2* __restrict__ P, int n) {
    int w = (blockIdx.x * 256 + threadIdx.x) >> 6;
    if (w >= n) return;
    int lane = threadIdx.x & 63;
    unsigned g = (unsigned)lane >> 4, sl = (unsigned)lane & 15u;
    uint2 o = offs2[w];
    int beg = (int)o.x, end = (int)o.y;
    f32x2 A01 = {0.f, 0.f}, A23 = {0.f, 0.f};

    unsigned selfU = ldG(G, (unsigned)w, sl);     // self-loop row, added post-merge
    for (int e = beg; e < end; e += 64) {         // degree-independent 64-edge bursts
        int i0 = e + (int)g;
        int vv[16];
#pragma unroll
        for (int k = 0; k < 16; ++k)              // unconditional: bucket pad makes safe
            vv[k] = csr[i0 + 4 * k];
        unsigned uu[16];
#pragma unroll
        for (int k = 0; k < 16; ++k) {
            unsigned c = (i0 + 4 * k < end) ? (unsigned)vv[k] : (unsigned)n;
            uu[k] = ldG(G, c, sl);
        }
#pragma unroll
        for (int k = 0; k < 16; ++k) {
            A01 += __builtin_amdgcn_cvt_pk_f32_fp8((int)uu[k], false);
            A23 += __builtin_amdgcn_cvt_pk_f32_fp8((int)uu[k], true);
        }
    }
    float a0 = A01.x, a1 = A01.y, a2 = A23.x, a3 = A23.y;
    // merge the 4 edge-groups
    a0 += __shfl_xor(a0, 16, 64); a1 += __shfl_xor(a1, 16, 64);
    a2 += __shfl_xor(a2, 16, 64); a3 += __shfl_xor(a3, 16, 64);
    a0 += __shfl_xor(a0, 32, 64); a1 += __shfl_xor(a1, 32, 64);
    a2 += __shfl_xor(a2, 32, 64); a3 += __shfl_xor(a3, 32, 64);
    // add self-loop once (all group-replicas do the identical add)
    A01 = __builtin_amdgcn_cvt_pk_f32_fp8((int)selfU, false);
    A23 = __builtin_amdgcn_cvt_pk_f32_fp8((int)selfU, true);
    a0 += A01.x; a1 += A01.y; a2 += A23.x; a3 += A23.y;
    float d = dinv[w];
    float4 bb = ((const float4*)bias)[sl];        // b1 dims 4sl..4sl+3
    float v0 = fmaxf(fmaf(a0, d, bb.x), 0.f);
    float v1 = fmaxf(fmaf(a1, d, bb.y), 0.f);
    float v2 = fmaxf(fmaf(a2, d, bb.z), 0.f);
    float v3 = fmaxf(fmaf(a3, d, bb.w), 0.f);
    float4 wa = ((const float4*)Wfold)[2 * sl];       // dims 4sl, 4sl+1
    float4 wb = ((const float4*)Wfold)[2 * sl + 1];   // dims 4sl+2, 4sl+3
    float px = v0 * wa.x + v1 * wa.z + v2 * wb.x + v3 * wb.z;
    float py = v0 * wa.y + v1 * wa.w + v2 * wb.y + v3 * wb.w;
    px += __shfl_xor(px, 1, 64); py += __shfl_xor(py, 1, 64);
    px += __shfl_xor(px, 2, 64); py += __shfl_xor(py, 2, 64);
    px += __shfl_xor(px, 4, 64); py += __shfl_xor(py, 4, 64);
    px += __shfl_xor(px, 8, 64); py += __shfl_xor(py, 8, 64);
    if (lane == 0) P[w] = make_float2(px * d, py * d);
}

// ---- gather-2 on P + fused softmax partials; 16-lane group per node ----
// 64-edge chunks: 4 unconditional csr loads + 4 P loads in flight; OOB -> P[n]=0
__global__ __launch_bounds__(256) void k_gather2(const int* __restrict__ csr,
                                                 const uint2* __restrict__ offs2,
                                                 const float2* __restrict__ P,
                                                 const float* __restrict__ dinv,
                                                 const float* __restrict__ bconst,
                                                 float* __restrict__ logits,
                                                 float4* __restrict__ partials, int n) {
    __shared__ float sml[16][2];
    int t = threadIdx.x;
    int w = (blockIdx.x * 256 + t) >> 4;
    int sl = t & 15;
    int grp = t >> 4;
    bool valid = (w < n);
    uint2 o = valid ? offs2[w] : make_uint2(0u, 0u);
    int beg = (int)o.x, end = (int)o.y;
    float ax = 0.f, ay = 0.f;
    for (int e = beg; e < end; e += 64) {
        int i0 = e + sl;
        int vv[4];
#pragma unroll
        for (int k = 0; k < 4; ++k)               // unconditional: bucket pad makes safe
            vv[k] = csr[i0 + 16 * k];
#pragma unroll
        for (int k = 0; k < 4; ++k) {
            unsigned j = (i0 + 16 * k < end) ? (unsigned)vv[k] : (unsigned)n;
            float2 p = *(const float2*)((const char*)P + (j << 3));
            ax += p.x; ay += p.y;
        }
    }
    ax += __shfl_xor(ax, 1, 64); ay += __shfl_xor(ay, 1, 64);
    ax += __shfl_xor(ax, 2, 64); ay += __shfl_xor(ay, 2, 64);
    ax += __shfl_xor(ax, 4, 64); ay += __shfl_xor(ay, 4, 64);
    ax += __shfl_xor(ax, 8, 64); ay += __shfl_xor(ay, 8, 64);
    float l0 = -3.4e38f, l1 = -3.4e38f;
    if (valid && sl == 0) {
        float2 self = P[w];
        float d = dinv[w];
        l0 = d * (self.x + ax) + bconst[0];
        l1 = d * (self.y + ay) + bconst[1];
        logits[w * 2]     = l0;
        logits[w * 2 + 1] = l1;
    }
    if (sl == 0) { sml[grp][0] = l0; sml[grp][1] = l1; }
    __syncthreads();
    if (t < 16) {                                 // block softmax partial (16 nodes)
        float a = sml[t][0], bv = sml[t][1];
        float m0 = a, m1 = bv;
#pragma unroll
        for (int d = 1; d < 16; d <<= 1) {
            m0 = fmaxf(m0, __shfl_xor(m0, d, 64));
            m1 = fmaxf(m1, __shfl_xor(m1, d, 64));
        }
        float e0 = (a > -1e38f) ? __expf(a - m0) : 0.f;
        float e1 = (bv > -1e38f) ? __expf(bv - m1) : 0.f;
#pragma unroll
        for (int d = 1; d < 16; d <<= 1) {
            e0 += __shfl_xor(e0, d, 64);
            e1 += __shfl_xor(e1, d, 64);
        }
        if (t == 0) partials[blockIdx.x] = make_float4(m0, e0, m1, e1);
    }
}

// ---- softmax finalize: each block merges all partials, then normalizes ----
__global__ __launch_bounds__(256) void k_sm_final(const float* __restrict__ logits,
                                                  const float4* __restrict__ partials,
                                                  float* __restrict__ out, int n, int nbp) {
    __shared__ float m0s[256], s0s[256], m1s[256], s1s[256];
    int t = threadIdx.x;
    float m0 = -3.4e38f, s0 = 0.f, m1 = -3.4e38f, s1 = 0.f;
    for (int i = t; i < nbp; i += 256) {
        float4 p = partials[i];
        float M = fmaxf(m0, p.x);
        s0 = s0 * __expf(m0 - M) + p.y * __expf(p.x - M); m0 = M;
        M = fmaxf(m1, p.z);
        s1 = s1 * __expf(m1 - M) + p.w * __expf(p.z - M); m1 = M;
    }
    m0s[t] = m0; s0s[t] = s0; m1s[t] = m1; s1s[t] = s1;
    __syncthreads();
    for (int s = 128; s > 0; s >>= 1) {
        if (t < s) {
            float Ma = m0s[t], Mb = m0s[t + s];
            float M = fmaxf(Ma, Mb);
            s0s[t] = s0s[t] * __expf(Ma - M) + s0s[t + s] * __expf(Mb - M);
            m0s[t] = M;
            Ma = m1s[t]; Mb = m1s[t + s];
            M = fmaxf(Ma, Mb);
            s1s[t] = s1s[t] * __expf(Ma - M) + s1s[t + s] * __expf(Mb - M);
            m1s[t] = M;
        }
        __syncthreads();
    }
    float M0 = m0s[0], inv0 = 1.f / s0s[0];
    float M1 = m1s[0], inv1 = 1.f / s1s[0];
    int i = blockIdx.x * 256 + t;
    if (i < n) {
        out[i * 2]     = __expf(logits[i * 2]     - M0) * inv0;
        out[i * 2 + 1] = __expf(logits[i * 2 + 1] - M1) * inv1;
    }
}

extern "C" void kernel_launch(void* const* d_in, const int* in_sizes, int n_in,
                              void* d_out, int out_size, void* d_ws, size_t ws_size,
                              hipStream_t stream) {
    const float* x   = (const float*)d_in[0];
    const int*   ei  = (const int*)d_in[1];
    const float* W1  = (const float*)d_in[2];
    const float* b1  = (const float*)d_in[3];
    const float* W2  = (const float*)d_in[4];
    const float* b2  = (const float*)d_in[5];
    const float* Wl1 = (const float*)d_in[6];
    const float* bl1 = (const float*)d_in[7];
    const float* Wl2 = (const float*)d_in[8];
    const float* bl2 = (const float*)d_in[9];
    float* out = (float*)d_out;

    int N = in_sizes[0] / F_IN;   // 100000
    int E = in_sizes[1] / 2;      // 3200000
    const int* esrc = ei;
    const int* edst = ei + E;

    int nbuck = (N + 255) / 256;  // 391 coarse buckets of 256 nodes

    char* ws = (char*)d_ws;
    size_t off = 0;
    auto alloc = [&](size_t bytes) { void* p = ws + off; off += (bytes + 255) & ~(size_t)255; return p; };
    int*            cursor = (int*)alloc((size_t)NBMAX * 4);
    float*          dinv   = (float*)alloc((size_t)N * 4);
    uint2*          offs2  = (uint2*)alloc((size_t)N * 8);               // {beg,end}/node
    int*            csr    = (int*)alloc((size_t)nbuck * CAP * 4);       // 14.8 MB padded
    unsigned*       ebuf   = (unsigned*)alloc((size_t)nbuck * CAP * 4);  // 14.8 MB padded
    unsigned*       gbuf   = (unsigned*)alloc((size_t)(N + 1) * 64);     // fp8 + zero pad row
    float*          Wfold  = (float*)alloc(64 * 2 * 4);
    float*          bconst = (float*)alloc(2 * 4);
    float2*         P      = (float2*)alloc((size_t)(N + 1) * 8);        // + zero pad row
    float*          logits = (float*)alloc((size_t)N * 2 * 4);
    int qb = (N * 16 + 255) / 256;         // gather2 blocks (16 nodes each)
    float4*         partials = (float4*)alloc((size_t)qb * 16);

    hipMemsetAsync(cursor, 0, NBMAX * sizeof(int), stream);

    int tiles = (E + TILE1 - 1) / TILE1;   // 391
    int mb = (N + 63) / 64;
    int wb = (N * 64 + 255) / 256;         // wave-per-node grid (k_gfold)
    int nb = (N + 255) / 256;

    // CSR build (padded-bucket layout; no global count/scan kernel needed)
    k_part1<<<tiles, 1024, 0, stream>>>(esrc, edst, cursor, ebuf, E, nbuck);
    k_part2<<<nbuck, 1024, 0, stream>>>(ebuf, cursor, csr, offs2, dinv, N);

    // layer 1 GEMM: G1 = fp8((x@W1)*dinv) ; block 0 folds Wfold/bconst + zeroes pads
    k_gemm_mfma<128, false><<<mb, 256, 0, stream>>>(x, W1, dinv, gbuf, N,
                                                    W2, b2, Wl1, bl1, Wl2, bl2,
                                                    Wfold, bconst, P);

    // gather-1 + relu + fold: P = dinv * (relu(dinv*(G1[d]+sum G1[src]) + b1) @ Wfold)
    k_gfold<<<wb, 256, 0, stream>>>(csr, offs2, gbuf, dinv, b1, Wfold, P, N);

    // gather-2 on P -> logits + per-block softmax partials
    k_gather2<<<qb, 256, 0, stream>>>(csr, offs2, P, dinv, bconst, logits, partials, N);

    // softmax finalize (merge partials + normalize)
    k_sm_final<<<nb, 256, 0, stream>>>(logits, partials, out, N, qb);
}

// Round 11
// 226.501 us; speedup vs baseline: 1.1363x; 1.0067x over previous
//
#include <hip/hip_runtime.h>

#define F_IN 128
#define NBMAX 512      // max coarse buckets (256 nodes each)
#define TILE1 8192     // edges per partition tile
#define CAP   9472     // padded per-bucket capacity (mean 8184, sigma~90 -> 14 sigma)
#define CAP2  10240    // pass-2 LDS staging capacity

typedef __attribute__((ext_vector_type(8))) short short8;
typedef __attribute__((ext_vector_type(4))) float f32x4;
typedef __attribute__((ext_vector_type(2))) float f32x2;

__device__ __forceinline__ unsigned short f2bf(float f) {   // RNE float->bf16
    unsigned u = __float_as_uint(f);
    u += 0x7fffu + ((u >> 16) & 1u);
    return (unsigned short)(u >> 16);
}

// single f32 -> fp8(e4m3) byte via HW conversion (RNE, saturating)
__device__ __forceinline__ unsigned char f2fp8(float f) {
    return (unsigned char)(__builtin_amdgcn_cvt_pk_fp8_f32(f, f, 0, false) & 0xff);
}

// G row gather with 32-bit byte offset -> saddr-form global_load (1 VALU/addr)
__device__ __forceinline__ unsigned ldG(const unsigned* __restrict__ G,
                                        unsigned c, unsigned sl) {
    return *(const unsigned*)((const char*)G + ((c << 6) + (sl << 2)));
}

// ---- pass 1: LDS-staged partition into padded coarse buckets ----
// bucket b owns ebuf[b*CAP, b*CAP+CAP); blocks claim sub-ranges via cursor atomics
__global__ __launch_bounds__(1024) void k_part1(const int* __restrict__ src,
                                                const int* __restrict__ dst,
                                                int* __restrict__ cursor,
                                                unsigned* __restrict__ ebuf,
                                                int E, int nb) {
    __shared__ unsigned staged[TILE1];
    __shared__ unsigned short sbuck[TILE1];
    __shared__ int hist[NBMAX], lbase[NBMAX], lcur[NBMAX], gbase[NBMAX];
    int t = threadIdx.x;
    for (int i = t; i < nb; i += 1024) hist[i] = 0;
    __syncthreads();
    int base = blockIdx.x * TILE1;
    int end = min(base + TILE1, E);
    int dreg[8];                                  // dst cached in regs: single read
#pragma unroll
    for (int k = 0; k < 8; ++k) {
        int i = base + t + 1024 * k;
        dreg[k] = (i < end) ? dst[i] : -1;
    }
#pragma unroll
    for (int k = 0; k < 8; ++k)
        if (dreg[k] >= 0) atomicAdd(&hist[dreg[k] >> 8], 1);
    __syncthreads();
    if (t < 64) {                                // single-wave chunked scan
        int carry = 0;
        for (int c = 0; c < (nb + 63) / 64; ++c) {
            int idx = c * 64 + t;
            int v = (idx < nb) ? hist[idx] : 0;
            int inc = v;
            for (int d = 1; d < 64; d <<= 1) {
                int u = __shfl_up(inc, d, 64);
                if (t >= d) inc += u;
            }
            if (idx < nb) { int ex = carry + inc - v; lbase[idx] = ex; lcur[idx] = ex; }
            carry += __shfl(inc, 63, 64);
        }
    }
    __syncthreads();
    for (int i = t; i < nb; i += 1024)
        gbase[i] = i * CAP + (hist[i] ? atomicAdd(&cursor[i], hist[i]) : 0);
#pragma unroll
    for (int k = 0; k < 8; ++k) {
        if (dreg[k] < 0) continue;
        int i = base + t + 1024 * k;
        int d = dreg[k];
        int b = d >> 8;
        int r = atomicAdd(&lcur[b], 1);
        staged[r] = ((unsigned)src[i] << 8) | (unsigned)(d & 255);
        sbuck[r] = (unsigned short)b;
    }
    __syncthreads();
    int cnt = end - base;
    for (int i = t; i < cnt; i += 1024) {
        int b = sbuck[i];
        __builtin_nontemporal_store(staged[i], &ebuf[gbase[b] + (i - lbase[b])]);
    }
}

// ---- pass 2: per-bucket 256-bin counting sort; emits csr, offs2{beg,end}, dinv ----
// single ebuf pass: entries held in registers across the scan (CAP <= 1024*10)
__global__ __launch_bounds__(1024) void k_part2(const unsigned* __restrict__ ebuf,
                                                const int* __restrict__ cursor,
                                                int* __restrict__ csr,
                                                uint2* __restrict__ offs2,
                                                float* __restrict__ dinv, int n) {
    __shared__ unsigned staged[CAP2];
    __shared__ int hist[256], lcur[256];
    int t = threadIdx.x;
    int b = blockIdx.x;
    int beg = b * CAP;
    int cnt = cursor[b];
    int end = beg + cnt;
    if (t < 256) hist[t] = 0;
    __syncthreads();
    unsigned er[10];                              // bucket entries in registers
#pragma unroll
    for (int k = 0; k < 10; ++k) {
        int i = beg + t + 1024 * k;
        er[k] = (i < end) ? ebuf[i] : 0xffffffffu;   // sentinel: entries < 2^25
        if (er[k] != 0xffffffffu) atomicAdd(&hist[er[k] & 255u], 1);
    }
    __syncthreads();
    if (t < 64) {
        int carry = 0;
        for (int c = 0; c < 4; ++c) {
            int idx = c * 64 + t;
            int v = hist[idx];
            int inc = v;
            for (int d = 1; d < 64; d <<= 1) {
                int u = __shfl_up(inc, d, 64);
                if (t >= d) inc += u;
            }
            int ex = carry + inc - v;
            lcur[idx] = ex;
            int node = b * 256 + idx;
            if (node < n) {
                offs2[node] = make_uint2((unsigned)(beg + ex), (unsigned)(beg + ex + v));
                dinv[node] = rsqrtf((float)(v + 1));
            }
            carry += __shfl(inc, 63, 64);
        }
    }
    __syncthreads();
#pragma unroll
    for (int k = 0; k < 10; ++k) {                // scatter from registers (no re-read)
        if (er[k] != 0xffffffffu) {
            int r = atomicAdd(&lcur[(int)(er[k] & 255u)], 1);
            staged[r] = er[k] >> 8;
        }
    }
    __syncthreads();
    for (int i = t; i < cnt; i += 1024)
        csr[beg + i] = (int)staged[i];            // plain store: L2-warm for gathers
    if (t < 64) csr[end + t] = n;   // 64-entry load-safety pad (unconditional burst loads)
}

// ---- MFMA GEMM: G[n][64](fp8 e4m3) = (X[n][K] @ W[K][64]) * dinv[n] ----
// block 0 additionally folds Wfold = W2@Wl1@Wl2, bconst = b2@Wc + bl1@Wl2 + bl2,
// zeroes pad rows G[n] and P[n]
template<int K, bool INBF16>
__global__ __launch_bounds__(256) void k_gemm_mfma(const void* __restrict__ Xv,
                                                   const float* __restrict__ W,
                                                   const float* __restrict__ dinv,
                                                   unsigned* __restrict__ G, int n,
                                                   const float* __restrict__ W2,
                                                   const float* __restrict__ b2,
                                                   const float* __restrict__ Wl1,
                                                   const float* __restrict__ bl1,
                                                   const float* __restrict__ Wl2,
                                                   const float* __restrict__ bl2,
                                                   float* __restrict__ Wfold,
                                                   float* __restrict__ bconst,
                                                   float2* __restrict__ P) {
    constexpr int AST = K + 8;
    __shared__ unsigned short A_lds[64 * AST];
    __shared__ unsigned short Wt_lds[64 * AST];
    __shared__ unsigned char C8[64 * 68];   // fp8 staging, row stride 68 B
    __shared__ float Wc[64][2];
    __shared__ float bc0[2];
    int t = threadIdx.x;
    int base = blockIdx.x * 64;

    if (blockIdx.x == 0) {                  // folded k_wfold + pad-row zeroes
        if (t < 128) {
            int k = t >> 1, c = t & 1;
            float s = 0.f;
            for (int m = 0; m < 32; ++m) s += Wl1[k * 32 + m] * Wl2[m * 2 + c];
            Wc[k][c] = s;
        } else if (t < 130) {
            int c = t - 128;
            float s = bl2[c];
            for (int m = 0; m < 32; ++m) s += bl1[m] * Wl2[m * 2 + c];
            bc0[c] = s;
        } else if (t == 200) {
            P[n] = make_float2(0.f, 0.f);         // zero pad row P[n]
        } else if (t >= 240 && t < 256) {
            G[(size_t)n * 16 + (t - 240)] = 0u;   // zero row G[n]
        }
        __syncthreads();
        if (t < 128) {
            int k = t >> 1, c = t & 1;
            float s = 0.f;
            for (int j = 0; j < 64; ++j) s += W2[k * 64 + j] * Wc[j][c];
            Wfold[k * 2 + c] = s;
        } else if (t < 130) {
            int c = t - 128;
            float s = bc0[c];
            for (int j = 0; j < 64; ++j) s += b2[j] * Wc[j][c];
            bconst[c] = s;
        }
    }

    for (int idx = t; idx < K * 64; idx += 256) {
        int k = idx >> 6, nn = idx & 63;
        Wt_lds[nn * AST + k] = f2bf(W[idx]);
    }
    if (!INBF16) {
        const f32x4* X4 = (const f32x4*)Xv;
        constexpr int F4 = K / 4;
        for (int idx = t; idx < 64 * F4; idx += 256) {
            int row = idx / F4, c4 = idx % F4;
            f32x4 f = {0.f, 0.f, 0.f, 0.f};
            if (base + row < n) f = X4[(size_t)base * F4 + idx];
            unsigned p0 = (unsigned)f2bf(f.x) | ((unsigned)f2bf(f.y) << 16);
            unsigned p1 = (unsigned)f2bf(f.z) | ((unsigned)f2bf(f.w) << 16);
            *(uint2*)&A_lds[row * AST + c4 * 4] = make_uint2(p0, p1);
        }
    } else {
        const unsigned* H32 = (const unsigned*)Xv;
        constexpr int U2 = K / 2;
        for (int idx = t; idx < 64 * U2; idx += 256) {
            int row = idx / U2, c2 = idx % U2;
            unsigned u = 0;
            if (base + row < n) u = H32[(size_t)base * U2 + idx];
            *(unsigned*)&A_lds[row * AST + c2 * 2] = u;
        }
    }
    __syncthreads();

    int lane = t & 63, w = t >> 6;
    int q = lane >> 4, m = lane & 15;
    f32x4 acc0 = {0,0,0,0}, acc1 = {0,0,0,0}, acc2 = {0,0,0,0}, acc3 = {0,0,0,0};
    const unsigned short* arow = &A_lds[(16 * w + m) * AST + q * 8];
#pragma unroll
    for (int s = 0; s < K / 32; ++s) {
        short8 a  = *(const short8*)(arow + s * 32);
        short8 w0 = *(const short8*)&Wt_lds[ m       * AST + s * 32 + q * 8];
        short8 w1 = *(const short8*)&Wt_lds[(16 + m) * AST + s * 32 + q * 8];
        short8 w2 = *(const short8*)&Wt_lds[(32 + m) * AST + s * 32 + q * 8];
        short8 w3 = *(const short8*)&Wt_lds[(48 + m) * AST + s * 32 + q * 8];
        acc0 = __builtin_amdgcn_mfma_f32_16x16x32_bf16(a, w0, acc0, 0, 0, 0);
        acc1 = __builtin_amdgcn_mfma_f32_16x16x32_bf16(a, w1, acc1, 0, 0, 0);
        acc2 = __builtin_amdgcn_mfma_f32_16x16x32_bf16(a, w2, acc2, 0, 0, 0);
        acc3 = __builtin_amdgcn_mfma_f32_16x16x32_bf16(a, w3, acc3, 0, 0, 0);
    }
    float dv[4];
#pragma unroll
    for (int r = 0; r < 4; ++r) {
        int node = base + 16 * w + q * 4 + r;
        dv[r] = (node < n) ? dinv[node] : 0.f;
    }
#pragma unroll
    for (int r = 0; r < 4; ++r) {
        int row = 16 * w + q * 4 + r;
        C8[row * 68 + m]      = f2fp8(acc0[r] * dv[r]);
        C8[row * 68 + 16 + m] = f2fp8(acc1[r] * dv[r]);
        C8[row * 68 + 32 + m] = f2fp8(acc2[r] * dv[r]);
        C8[row * 68 + 48 + m] = f2fp8(acc3[r] * dv[r]);
    }
    __syncthreads();
    for (int idx = t; idx < 1024; idx += 256) {
        int row = idx >> 4, c4 = idx & 15;
        int node = base + row;
        if (node < n) G[(size_t)node * 16 + c4] = *(const unsigned*)&C8[row * 68 + c4 * 4];
    }
}

// ---- gather-1 + fused fold on fp8 G; 16 lanes/row ----
// 64-edge bursts: 16 csr loads (unconditional, pad-safe) + 16 G loads in flight;
// OOB slots value-clamp to zero row G[n]
__global__ __launch_bounds__(256) void k_gfold(const int* __restrict__ csr,
                                               const uint2* __restrict__ offs2,
                                               const unsigned* __restrict__ G,
                                               const float* __restrict__ dinv,
                                               const float* __restrict__ bias,
                                               const float* __restrict__ Wfold,
                                               float2* __restrict__ P, int n) {
    int w = (blockIdx.x * 256 + threadIdx.x) >> 6;
    if (w >= n) return;
    int lane = threadIdx.x & 63;
    unsigned g = (unsigned)lane >> 4, sl = (unsigned)lane & 15u;
    uint2 o = offs2[w];
    int beg = (int)o.x, end = (int)o.y;
    f32x2 A01 = {0.f, 0.f}, A23 = {0.f, 0.f};

    unsigned selfU = ldG(G, (unsigned)w, sl);     // self-loop row, added post-merge
    for (int e = beg; e < end; e += 64) {         // degree-independent 64-edge bursts
        int i0 = e + (int)g;
        int vv[16];
#pragma unroll
        for (int k = 0; k < 16; ++k)              // unconditional: bucket pad makes safe
            vv[k] = csr[i0 + 4 * k];
        unsigned uu[16];
#pragma unroll
        for (int k = 0; k < 16; ++k) {
            unsigned c = (i0 + 4 * k < end) ? (unsigned)vv[k] : (unsigned)n;
            uu[k] = ldG(G, c, sl);
        }
#pragma unroll
        for (int k = 0; k < 16; ++k) {
            A01 += __builtin_amdgcn_cvt_pk_f32_fp8((int)uu[k], false);
            A23 += __builtin_amdgcn_cvt_pk_f32_fp8((int)uu[k], true);
        }
    }
    float a0 = A01.x, a1 = A01.y, a2 = A23.x, a3 = A23.y;
    // merge the 4 edge-groups
    a0 += __shfl_xor(a0, 16, 64); a1 += __shfl_xor(a1, 16, 64);
    a2 += __shfl_xor(a2, 16, 64); a3 += __shfl_xor(a3, 16, 64);
    a0 += __shfl_xor(a0, 32, 64); a1 += __shfl_xor(a1, 32, 64);
    a2 += __shfl_xor(a2, 32, 64); a3 += __shfl_xor(a3, 32, 64);
    // add self-loop once (all group-replicas do the identical add)
    A01 = __builtin_amdgcn_cvt_pk_f32_fp8((int)selfU, false);
    A23 = __builtin_amdgcn_cvt_pk_f32_fp8((int)selfU, true);
    a0 += A01.x; a1 += A01.y; a2 += A23.x; a3 += A23.y;
    float d = dinv[w];
    float4 bb = ((const float4*)bias)[sl];        // b1 dims 4sl..4sl+3
    float v0 = fmaxf(fmaf(a0, d, bb.x), 0.f);
    float v1 = fmaxf(fmaf(a1, d, bb.y), 0.f);
    float v2 = fmaxf(fmaf(a2, d, bb.z), 0.f);
    float v3 = fmaxf(fmaf(a3, d, bb.w), 0.f);
    float4 wa = ((const float4*)Wfold)[2 * sl];       // dims 4sl, 4sl+1
    float4 wb = ((const float4*)Wfold)[2 * sl + 1];   // dims 4sl+2, 4sl+3
    float px = v0 * wa.x + v1 * wa.z + v2 * wb.x + v3 * wb.z;
    float py = v0 * wa.y + v1 * wa.w + v2 * wb.y + v3 * wb.w;
    px += __shfl_xor(px, 1, 64); py += __shfl_xor(py, 1, 64);
    px += __shfl_xor(px, 2, 64); py += __shfl_xor(py, 2, 64);
    px += __shfl_xor(px, 4, 64); py += __shfl_xor(py, 4, 64);
    px += __shfl_xor(px, 8, 64); py += __shfl_xor(py, 8, 64);
    if (lane == 0) P[w] = make_float2(px * d, py * d);
}

// ---- gather-2 on P + fused softmax partials; 16-lane group per node ----
// 64-edge chunks: 4 unconditional csr loads + 4 P loads in flight; OOB -> P[n]=0
__global__ __launch_bounds__(256) void k_gather2(const int* __restrict__ csr,
                                                 const uint2* __restrict__ offs2,
                                                 const float2* __restrict__ P,
                                                 const float* __restrict__ dinv,
                                                 const float* __restrict__ bconst,
                                                 float* __restrict__ logits,
                                                 float4* __restrict__ partials, int n) {
    __shared__ float sml[16][2];
    int t = threadIdx.x;
    int w = (blockIdx.x * 256 + t) >> 4;
    int sl = t & 15;
    int grp = t >> 4;
    bool valid = (w < n);
    uint2 o = valid ? offs2[w] : make_uint2(0u, 0u);
    int beg = (int)o.x, end = (int)o.y;
    float ax = 0.f, ay = 0.f;
    for (int e = beg; e < end; e += 64) {
        int i0 = e + sl;
        int vv[4];
#pragma unroll
        for (int k = 0; k < 4; ++k)               // unconditional: bucket pad makes safe
            vv[k] = csr[i0 + 16 * k];
#pragma unroll
        for (int k = 0; k < 4; ++k) {
            unsigned j = (i0 + 16 * k < end) ? (unsigned)vv[k] : (unsigned)n;
            float2 p = *(const float2*)((const char*)P + (j << 3));
            ax += p.x; ay += p.y;
        }
    }
    ax += __shfl_xor(ax, 1, 64); ay += __shfl_xor(ay, 1, 64);
    ax += __shfl_xor(ax, 2, 64); ay += __shfl_xor(ay, 2, 64);
    ax += __shfl_xor(ax, 4, 64); ay += __shfl_xor(ay, 4, 64);
    ax += __shfl_xor(ax, 8, 64); ay += __shfl_xor(ay, 8, 64);
    float l0 = -3.4e38f, l1 = -3.4e38f;
    if (valid && sl == 0) {
        float2 self = P[w];
        float d = dinv[w];
        l0 = d * (self.x + ax) + bconst[0];
        l1 = d * (self.y + ay) + bconst[1];
        logits[w * 2]     = l0;
        logits[w * 2 + 1] = l1;
    }
    if (sl == 0) { sml[grp][0] = l0; sml[grp][1] = l1; }
    __syncthreads();
    if (t < 16) {                                 // block softmax partial (16 nodes)
        float a = sml[t][0], bv = sml[t][1];
        float m0 = a, m1 = bv;
#pragma unroll
        for (int d = 1; d < 16; d <<= 1) {
            m0 = fmaxf(m0, __shfl_xor(m0, d, 64));
            m1 = fmaxf(m1, __shfl_xor(m1, d, 64));
        }
        float e0 = (a > -1e38f) ? __expf(a - m0) : 0.f;
        float e1 = (bv > -1e38f) ? __expf(bv - m1) : 0.f;
#pragma unroll
        for (int d = 1; d < 16; d <<= 1) {
            e0 += __shfl_xor(e0, d, 64);
            e1 += __shfl_xor(e1, d, 64);
        }
        if (t == 0) partials[blockIdx.x] = make_float4(m0, e0, m1, e1);
    }
}

// ---- softmax finalize: each block merges all partials, then normalizes ----
__global__ __launch_bounds__(256) void k_sm_final(const float* __restrict__ logits,
                                                  const float4* __restrict__ partials,
                                                  float* __restrict__ out, int n, int nbp) {
    __shared__ float m0s[256], s0s[256], m1s[256], s1s[256];
    int t = threadIdx.x;
    float m0 = -3.4e38f, s0 = 0.f, m1 = -3.4e38f, s1 = 0.f;
    for (int i = t; i < nbp; i += 256) {
        float4 p = partials[i];
        float M = fmaxf(m0, p.x);
        s0 = s0 * __expf(m0 - M) + p.y * __expf(p.x - M); m0 = M;
        M = fmaxf(m1, p.z);
        s1 = s1 * __expf(m1 - M) + p.w * __expf(p.z - M); m1 = M;
    }
    m0s[t] = m0; s0s[t] = s0; m1s[t] = m1; s1s[t] = s1;
    __syncthreads();
    for (int s = 128; s > 0; s >>= 1) {
        if (t < s) {
            float Ma = m0s[t], Mb = m0s[t + s];
            float M = fmaxf(Ma, Mb);
            s0s[t] = s0s[t] * __expf(Ma - M) + s0s[t + s] * __expf(Mb - M);
            m0s[t] = M;
            Ma = m1s[t]; Mb = m1s[t + s];
            M = fmaxf(Ma, Mb);
            s1s[t] = s1s[t] * __expf(Ma - M) + s1s[t + s] * __expf(Mb - M);
            m1s[t] = M;
        }
        __syncthreads();
    }
    float M0 = m0s[0], inv0 = 1.f / s0s[0];
    float M1 = m1s[0], inv1 = 1.f / s1s[0];
    int i = blockIdx.x * 256 + t;
    if (i < n) {
        out[i * 2]     = __expf(logits[i * 2]     - M0) * inv0;
        out[i * 2 + 1] = __expf(logits[i * 2 + 1] - M1) * inv1;
    }
}

extern "C" void kernel_launch(void* const* d_in, const int* in_sizes, int n_in,
                              void* d_out, int out_size, void* d_ws, size_t ws_size,
                              hipStream_t stream) {
    const float* x   = (const float*)d_in[0];
    const int*   ei  = (const int*)d_in[1];
    const float* W1  = (const float*)d_in[2];
    const float* b1  = (const float*)d_in[3];
    const float* W2  = (const float*)d_in[4];
    const float* b2  = (const float*)d_in[5];
    const float* Wl1 = (const float*)d_in[6];
    const float* bl1 = (const float*)d_in[7];
    const float* Wl2 = (const float*)d_in[8];
    const float* bl2 = (const float*)d_in[9];
    float* out = (float*)d_out;

    int N = in_sizes[0] / F_IN;   // 100000
    int E = in_sizes[1] / 2;      // 3200000
    const int* esrc = ei;
    const int* edst = ei + E;

    int nbuck = (N + 255) / 256;  // 391 coarse buckets of 256 nodes

    char* ws = (char*)d_ws;
    size_t off = 0;
    auto alloc = [&](size_t bytes) { void* p = ws + off; off += (bytes + 255) & ~(size_t)255; return p; };
    int*            cursor = (int*)alloc((size_t)NBMAX * 4);
    float*          dinv   = (float*)alloc((size_t)N * 4);
    uint2*          offs2  = (uint2*)alloc((size_t)N * 8);               // {beg,end}/node
    int*            csr    = (int*)alloc((size_t)nbuck * CAP * 4);       // 14.8 MB padded
    unsigned*       ebuf   = (unsigned*)alloc((size_t)nbuck * CAP * 4);  // 14.8 MB padded
    unsigned*       gbuf   = (unsigned*)alloc((size_t)(N + 1) * 64);     // fp8 + zero pad row
    float*          Wfold  = (float*)alloc(64 * 2 * 4);
    float*          bconst = (float*)alloc(2 * 4);
    float2*         P      = (float2*)alloc((size_t)(N + 1) * 8);        // + zero pad row
    float*          logits = (float*)alloc((size_t)N * 2 * 4);
    int qb = (N * 16 + 255) / 256;         // gather2 blocks (16 nodes each)
    float4*         partials = (float4*)alloc((size_t)qb * 16);

    hipMemsetAsync(cursor, 0, NBMAX * sizeof(int), stream);

    int tiles = (E + TILE1 - 1) / TILE1;   // 391
    int mb = (N + 63) / 64;
    int wb = (N * 64 + 255) / 256;         // wave-per-node grid (k_gfold)
    int nb = (N + 255) / 256;

    // CSR build (padded-bucket layout; single ebuf pass in part2)
    k_part1<<<tiles, 1024, 0, stream>>>(esrc, edst, cursor, ebuf, E, nbuck);
    k_part2<<<nbuck, 1024, 0, stream>>>(ebuf, cursor, csr, offs2, dinv, N);

    // layer 1 GEMM: G1 = fp8((x@W1)*dinv) ; block 0 folds Wfold/bconst + zeroes pads
    k_gemm_mfma<128, false><<<mb, 256, 0, stream>>>(x, W1, dinv, gbuf, N,
                                                    W2, b2, Wl1, bl1, Wl2, bl2,
                                                    Wfold, bconst, P);

    // gather-1 + relu + fold: P = dinv * (relu(dinv*(G1[d]+sum G1[src]) + b1) @ Wfold)
    k_gfold<<<wb, 256, 0, stream>>>(csr, offs2, gbuf, dinv, b1, Wfold, P, N);

    // gather-2 on P -> logits + per-block softmax partials
    k_gather2<<<qb, 256, 0, stream>>>(csr, offs2, P, dinv, bconst, logits, partials, N);

    // softmax finalize (merge partials + normalize)
    k_sm_final<<<nb, 256, 0, stream>>>(logits, partials, out, N, qb);
}